// Round 9
// baseline (342.689 us; speedup 1.0000x reference)
//
#include <hip/hip_runtime.h>
#include <hip/hip_fp16.h>
#include <math.h>

#define PI_F 3.14159265358979323846f

// Wave-local LDS sync (lanes lockstep); guide rule 18: sched_barrier after.
__device__ __forceinline__ void wave_sync() {
    asm volatile("s_waitcnt lgkmcnt(0)" ::: "memory");
    __builtin_amdgcn_sched_barrier(0);
}

// ---------------------------------------------------------------------------
// Block-shared twiddle table: Tw[j*17 + k1] = exp(-2*pi*i*j*k1/256).
// Padded stride 17 -> row-kernel reads (j varies across lanes, k1 fixed)
// hit 16 distinct even banks; col-kernel reads (j uniform per 16-lane group)
// are broadcasts. Built once per block, then __syncthreads.
// ---------------------------------------------------------------------------
__device__ __forceinline__ void build_twiddle(float2* Tw, int t) {
    int j = t & 15, k1 = t >> 4;               // 256 threads = full table
    float ang = -(2.f * PI_F / 256.f) * (float)(j * k1);
    float sn, cs; __sincosf(ang, &sn, &cs);
    Tw[j * 17 + k1] = make_float2(cs, sn);
    __syncthreads();
}

// ---------------------------------------------------------------------------
// FFT-16 fully in registers: Stockham radix-4 x2, natural order in/out.
// All twiddles compile-time. INV=0 fwd, INV=1 inv (unnormalized).
// Verified R5/R6 (absmax 0.031 << 0.129).
// ---------------------------------------------------------------------------
template<int INV>
__device__ __forceinline__ void fft16_reg(float* ar, float* ai) {
    const float S  = INV ? 1.f : -1.f;
    const float C8 = 0.92387953251128674f;
    const float S8 = 0.38268343236508977f;
    const float R2 = 0.70710678118654752f;
    const float w1r[4] = {1.f, C8, R2, S8}, w1s[4] = {0.f, S8, R2, C8};
    const float w2r[4] = {1.f, R2, 0.f, -R2}, w2s[4] = {0.f, R2, 1.f, R2};
    const float w3r[4] = {1.f, S8, -R2, -C8}, w3s[4] = {0.f, C8, R2, -S8};
    float tr[16], ti[16];
#pragma unroll
    for (int j = 0; j < 4; ++j) {            // stage 1 (m=1)
        float x0r = ar[j],    x0i = ai[j];
        float x1r = ar[j+4],  x1i = ai[j+4];
        float x2r = ar[j+8],  x2i = ai[j+8];
        float x3r = ar[j+12], x3i = ai[j+12];
        float t0r = x0r+x2r, t0i = x0i+x2i;
        float t2r = x0r-x2r, t2i = x0i-x2i;
        float t1r = x1r+x3r, t1i = x1i+x3i;
        float u3r = x1r-x3r, u3i = x1i-x3i;
        float t3r = -S*u3i,  t3i = S*u3r;
        float y0r = t0r+t1r, y0i = t0i+t1i;
        float y1r = t2r+t3r, y1i = t2i+t3i;
        float y2r = t0r-t1r, y2i = t0i-t1i;
        float y3r = t2r-t3r, y3i = t2i-t3i;
        float a1r = w1r[j], a1i = S*w1s[j];
        float a2r = w2r[j], a2i = S*w2s[j];
        float a3r = w3r[j], a3i = S*w3s[j];
        tr[4*j]   = y0r;               ti[4*j]   = y0i;
        tr[4*j+1] = a1r*y1r - a1i*y1i; ti[4*j+1] = a1r*y1i + a1i*y1r;
        tr[4*j+2] = a2r*y2r - a2i*y2i; ti[4*j+2] = a2r*y2i + a2i*y2r;
        tr[4*j+3] = a3r*y3r - a3i*y3i; ti[4*j+3] = a3r*y3i + a3i*y3r;
    }
#pragma unroll
    for (int j = 0; j < 4; ++j) {            // stage 2 (m=4), no twiddles
        float x0r = tr[j],    x0i = ti[j];
        float x1r = tr[j+4],  x1i = ti[j+4];
        float x2r = tr[j+8],  x2i = ti[j+8];
        float x3r = tr[j+12], x3i = ti[j+12];
        float t0r = x0r+x2r, t0i = x0i+x2i;
        float t2r = x0r-x2r, t2i = x0i-x2i;
        float t1r = x1r+x3r, t1i = x1i+x3i;
        float u3r = x1r-x3r, u3i = x1i-x3i;
        float t3r = -S*u3i,  t3i = S*u3r;
        ar[j]    = t0r+t1r;  ai[j]    = t0i+t1i;
        ar[j+4]  = t2r+t3r;  ai[j+4]  = t2i+t3i;
        ar[j+8]  = t0r-t1r;  ai[j+8]  = t0i-t1i;
        ar[j+12] = t2r-t3r;  ai[j+12] = t2i-t3i;
    }
}

// ---------------------------------------------------------------------------
// 256-pt FFT, 4-step (16x16), for a 16-thread group.
// In: thread j holds a[n1] = x[16*n1 + j]. Out: thread j holds X[16*k2 + j]
// in a[k2] (same residue-j layout -> chains into another 4-step directly).
// Split re/im f32 16x17 LDS transpose (R6 known-good: conflict-free for
// group strides 272/274, zero format conversions).
// Twiddle from the shared table: 1 b64 read + 1 cmul per element (replaces
// the serial chain's dependent cmul per element).
// BLOCKWIDE adds a pre-store barrier so Tr/Ti can be reused across calls.
// ---------------------------------------------------------------------------
template<int INV, bool BLOCKWIDE>
__device__ __forceinline__ void fft256_4step(float* ar, float* ai,
                                             float* Tr, float* Ti,
                                             const float2* Tw,
                                             int gbase, int j) {
    fft16_reg<INV>(ar, ai);
#pragma unroll
    for (int k1 = 0; k1 < 16; ++k1) {
        float2 w = Tw[j * 17 + k1];
        float wr = w.x;
        float wi = INV ? -w.y : w.y;         // conj for inverse
        float xr = ar[k1], xi = ai[k1];
        ar[k1] = xr*wr - xi*wi;
        ai[k1] = xr*wi + xi*wr;
    }
    if (BLOCKWIDE) __syncthreads();          // protect reused transpose buffer
#pragma unroll
    for (int k1 = 0; k1 < 16; ++k1) {
        Tr[gbase + k1*17 + j] = ar[k1];
        Ti[gbase + k1*17 + j] = ai[k1];
    }
    if (BLOCKWIDE) __syncthreads(); else wave_sync();
#pragma unroll
    for (int n2 = 0; n2 < 16; ++n2) {
        ar[n2] = Tr[gbase + j*17 + n2];
        ai[n2] = Ti[gbase + j*17 + n2];
    }
    fft16_reg<INV>(ar, ai);
}

// ---------------------------------------------------------------------------
// P1: forward row FFT of real x -> W1[img][n][m] (half2). 16 rows/block.
// ---------------------------------------------------------------------------
__global__ __launch_bounds__(256) void k_row_fft(const float* __restrict__ x,
                                                 __half2* __restrict__ W1) {
    __shared__ float Tr[4352], Ti[4352];
    __shared__ float2 Tw[272];
    int t = threadIdx.x, g = t >> 4, j = t & 15;
    build_twiddle(Tw, t);
    long row = (long)blockIdx.x * 16 + g;
    const float* src = x + row * 256;
    float ar[16], ai[16];
#pragma unroll
    for (int n1 = 0; n1 < 16; ++n1) { ar[n1] = src[n1*16 + j]; ai[n1] = 0.f; }
    fft256_4step<0, false>(ar, ai, Tr, Ti, Tw, g * 272, j);
    __half2* dst = W1 + row * 256;
#pragma unroll
    for (int k2 = 0; k2 < 16; ++k2) dst[k2*16 + j] = __floats2half2_rn(ar[k2], ai[k2]);
}

// ---------------------------------------------------------------------------
// P2+P3 fused: per 16-col tile, forward col FFT ONCE (kept in registers),
// then for GROUP slices: mul by F_s/65536, inverse col FFT, write Z_s.
// Table built once, reused by all 5 FFT passes.
// ---------------------------------------------------------------------------
template<int GROUP>
__global__ __launch_bounds__(256) void k_col_fused(const __half2* __restrict__ W1,
                                                   const float* __restrict__ fre,
                                                   const float* __restrict__ fim,
                                                   __half2* __restrict__ Z, int s0) {
    __shared__ float Tr[4384], Ti[4384];
    __shared__ float2 Tw[272];
    int t = threadIdx.x, c = t & 15, j = t >> 4;
    build_twiddle(Tw, t);
    int m0 = blockIdx.x * 16, img = blockIdx.y;
    const __half2* src = W1 + (size_t)img * 65536 + m0 + c;
    const float scale = 1.f / 65536.f;      // full ifft2 normalization
    float ar[16], ai[16];
#pragma unroll
    for (int n1 = 0; n1 < 16; ++n1) {
        __half2 v = src[(n1*16 + j) * 256];
        ar[n1] = __low2float(v); ai[n1] = __high2float(v);
    }
    fft256_4step<0, true>(ar, ai, Tr, Ti, Tw, c * 274, j);
    float xr[16], xi[16];
#pragma unroll
    for (int k2 = 0; k2 < 16; ++k2) { xr[k2] = ar[k2]; xi[k2] = ai[k2]; }

    for (int sl = 0; sl < GROUP; ++sl) {
        int s = s0 + sl;
        const float* fr = fre + (size_t)s * 65536 + m0 + c;
        const float* fi = fim + (size_t)s * 65536 + m0 + c;
#pragma unroll
        for (int k2 = 0; k2 < 16; ++k2) {
            int off = (16*k2 + j) * 256;
            float wr = fr[off] * scale, wi = fi[off] * scale;
            ar[k2] = xr[k2]*wr - xi[k2]*wi;
            ai[k2] = xr[k2]*wi + xi[k2]*wr;
        }
        fft256_4step<1, true>(ar, ai, Tr, Ti, Tw, c * 274, j);
        __half2* dst = Z + (size_t)sl * 8388608 + (size_t)img * 65536 + m0 + c;
#pragma unroll
        for (int k2 = 0; k2 < 16; ++k2)
            dst[(16*k2 + j) * 256] = __floats2half2_rn(ar[k2], ai[k2]);
    }
}

// ---------------------------------------------------------------------------
// P4 (batched over GROUP slices): inverse row FFT of Z_sl, |.| -> out.
// ---------------------------------------------------------------------------
__global__ __launch_bounds__(256) void k_row_ifft_abs(const __half2* __restrict__ Z,
                                                      float* __restrict__ out, int s0) {
    __shared__ float Tr[4352], Ti[4352];
    __shared__ float2 Tw[272];
    int t = threadIdx.x, g = t >> 4, j = t & 15;
    build_twiddle(Tw, t);
    int sl = blockIdx.y;
    long row = (long)blockIdx.x * 16 + g;   // img*256 + n
    long img = row >> 8, n = row & 255;
    const __half2* src = Z + (size_t)sl * 8388608 + row * 256;
    float ar[16], ai[16];
#pragma unroll
    for (int n1 = 0; n1 < 16; ++n1) {
        __half2 v = src[n1*16 + j];
        ar[n1] = __low2float(v); ai[n1] = __high2float(v);
    }
    fft256_4step<1, false>(ar, ai, Tr, Ti, Tw, g * 272, j);
    float* dst = out + ((img * 8 + (long)(s0 + sl)) * 256 + n) * 256;
#pragma unroll
    for (int k2 = 0; k2 < 16; ++k2)
        dst[k2*16 + j] = sqrtf(ar[k2]*ar[k2] + ai[k2]*ai[k2]);
}

// ---------------------------------------------------------------------------
extern "C" void kernel_launch(void* const* d_in, const int* in_sizes, int n_in,
                              void* d_out, int out_size, void* d_ws, size_t ws_size,
                              hipStream_t stream) {
    const float* x   = (const float*)d_in[0];   // [8,16,256,256] f32
    const float* fre = (const float*)d_in[1];   // [8,256,256]
    const float* fim = (const float*)d_in[2];   // [8,256,256]
    float* out = (float*)d_out;                 // [8,16,8,256,256] f32

    const size_t IMG_ELEMS = (size_t)128 * 65536;
    __half2* W1 = (__half2*)d_ws;                          // 33.5 MB
    __half2* Z  = (__half2*)((char*)d_ws + IMG_ELEMS * 4); // 33.5 MB x GROUP

    k_row_fft<<<dim3(2048), 256, 0, stream>>>(x, W1);

    if (ws_size >= IMG_ELEMS * 4 * 5) {        // W1 + 4 Z slices = 168 MB
        for (int s0 = 0; s0 < 8; s0 += 4) {
            k_col_fused<4><<<dim3(16, 128), 256, 0, stream>>>(W1, fre, fim, Z, s0);
            k_row_ifft_abs<<<dim3(2048, 4), 256, 0, stream>>>(Z, out, s0);
        }
    } else {                                   // fallback: slice-at-a-time
        for (int s = 0; s < 8; ++s) {
            k_col_fused<1><<<dim3(16, 128), 256, 0, stream>>>(W1, fre, fim, Z, s);
            k_row_ifft_abs<<<dim3(2048, 1), 256, 0, stream>>>(Z, out, s);
        }
    }
}

// Round 10
// 238.266 us; speedup vs baseline: 1.4383x; 1.4383x over previous
//
#include <hip/hip_runtime.h>
#include <hip/hip_fp16.h>
#include <math.h>

#define PI_F 3.14159265358979323846f

// Wave-local LDS sync (lanes lockstep); guide rule 18: sched_barrier after.
__device__ __forceinline__ void wave_sync() {
    asm volatile("s_waitcnt lgkmcnt(0)" ::: "memory");
    __builtin_amdgcn_sched_barrier(0);
}

// ---------------------------------------------------------------------------
// FFT-16 fully in registers: Stockham radix-4 x2, natural order in/out.
// All twiddles compile-time. INV=0 fwd, INV=1 inv (unnormalized).
// Verified R5/R6 (absmax 0.031 << 0.129).
// ---------------------------------------------------------------------------
template<int INV>
__device__ __forceinline__ void fft16_reg(float* ar, float* ai) {
    const float S  = INV ? 1.f : -1.f;
    const float C8 = 0.92387953251128674f;
    const float S8 = 0.38268343236508977f;
    const float R2 = 0.70710678118654752f;
    const float w1r[4] = {1.f, C8, R2, S8}, w1s[4] = {0.f, S8, R2, C8};
    const float w2r[4] = {1.f, R2, 0.f, -R2}, w2s[4] = {0.f, R2, 1.f, R2};
    const float w3r[4] = {1.f, S8, -R2, -C8}, w3s[4] = {0.f, C8, R2, -S8};
    float tr[16], ti[16];
#pragma unroll
    for (int j = 0; j < 4; ++j) {            // stage 1 (m=1)
        float x0r = ar[j],    x0i = ai[j];
        float x1r = ar[j+4],  x1i = ai[j+4];
        float x2r = ar[j+8],  x2i = ai[j+8];
        float x3r = ar[j+12], x3i = ai[j+12];
        float t0r = x0r+x2r, t0i = x0i+x2i;
        float t2r = x0r-x2r, t2i = x0i-x2i;
        float t1r = x1r+x3r, t1i = x1i+x3i;
        float u3r = x1r-x3r, u3i = x1i-x3i;
        float t3r = -S*u3i,  t3i = S*u3r;
        float y0r = t0r+t1r, y0i = t0i+t1i;
        float y1r = t2r+t3r, y1i = t2i+t3i;
        float y2r = t0r-t1r, y2i = t0i-t1i;
        float y3r = t2r-t3r, y3i = t2i-t3i;
        float a1r = w1r[j], a1i = S*w1s[j];
        float a2r = w2r[j], a2i = S*w2s[j];
        float a3r = w3r[j], a3i = S*w3s[j];
        tr[4*j]   = y0r;               ti[4*j]   = y0i;
        tr[4*j+1] = a1r*y1r - a1i*y1i; ti[4*j+1] = a1r*y1i + a1i*y1r;
        tr[4*j+2] = a2r*y2r - a2i*y2i; ti[4*j+2] = a2r*y2i + a2i*y2r;
        tr[4*j+3] = a3r*y3r - a3i*y3i; ti[4*j+3] = a3r*y3i + a3i*y3r;
    }
#pragma unroll
    for (int j = 0; j < 4; ++j) {            // stage 2 (m=4), no twiddles
        float x0r = tr[j],    x0i = ti[j];
        float x1r = tr[j+4],  x1i = ti[j+4];
        float x2r = tr[j+8],  x2i = ti[j+8];
        float x3r = tr[j+12], x3i = ti[j+12];
        float t0r = x0r+x2r, t0i = x0i+x2i;
        float t2r = x0r-x2r, t2i = x0i-x2i;
        float t1r = x1r+x3r, t1i = x1i+x3i;
        float u3r = x1r-x3r, u3i = x1i-x3i;
        float t3r = -S*u3i,  t3i = S*u3r;
        ar[j]    = t0r+t1r;  ai[j]    = t0i+t1i;
        ar[j+4]  = t2r+t3r;  ai[j+4]  = t2i+t3i;
        ar[j+8]  = t0r-t1r;  ai[j+8]  = t0i-t1i;
        ar[j+12] = t2r-t3r;  ai[j+12] = t2i-t3i;
    }
}

// ---------------------------------------------------------------------------
// 256-pt FFT, 4-step (16x16), for a 16-thread group.  (Exact R6 form: split
// re/im f32 16x17 LDS transpose -- conflict-free for group strides 272/274 --
// and the serial twiddle chain: minimal total issue slots; R7/R8/R9
// alternatives all measured slower.)
// In: thread j holds a[n1] = x[16*n1 + j]. Out: thread j holds X[16*k2 + j]
// in a[k2] (same residue-j layout -> chains into another 4-step directly).
// BLOCKWIDE adds a pre-store barrier so Tr/Ti can be reused across calls.
// ---------------------------------------------------------------------------
template<int INV, bool BLOCKWIDE>
__device__ __forceinline__ void fft256_4step(float* ar, float* ai,
                                             float* Tr, float* Ti,
                                             int gbase, int j) {
    fft16_reg<INV>(ar, ai);
    const float S = INV ? 1.f : -1.f;
    float sb, cb;
    __sincosf(S * (2.f * PI_F / 256.f) * (float)j, &sb, &cb);
    float wr = 1.f, wi = 0.f;
#pragma unroll
    for (int k1 = 0; k1 < 16; ++k1) {
        float xr = ar[k1], xi = ai[k1];
        ar[k1] = xr*wr - xi*wi;
        ai[k1] = xr*wi + xi*wr;
        float nwr = wr*cb - wi*sb;
        wi = wr*sb + wi*cb;
        wr = nwr;
    }
    if (BLOCKWIDE) __syncthreads();          // protect reused transpose buffer
#pragma unroll
    for (int k1 = 0; k1 < 16; ++k1) {
        Tr[gbase + k1*17 + j] = ar[k1];
        Ti[gbase + k1*17 + j] = ai[k1];
    }
    if (BLOCKWIDE) __syncthreads(); else wave_sync();
#pragma unroll
    for (int n2 = 0; n2 < 16; ++n2) {
        ar[n2] = Tr[gbase + j*17 + n2];
        ai[n2] = Ti[gbase + j*17 + n2];
    }
    fft16_reg<INV>(ar, ai);
}

// ---------------------------------------------------------------------------
// P1: forward row FFT of real x -> W1[img][n][m] (half2). 16 rows/block.
// x is read-once: nontemporal loads keep it from polluting L3 (W1 stays hot).
// ---------------------------------------------------------------------------
__global__ __launch_bounds__(256) void k_row_fft(const float* __restrict__ x,
                                                 __half2* __restrict__ W1) {
    __shared__ float Tr[4352], Ti[4352];
    int t = threadIdx.x, g = t >> 4, j = t & 15;
    long row = (long)blockIdx.x * 16 + g;
    const float* src = x + row * 256;
    float ar[16], ai[16];
#pragma unroll
    for (int n1 = 0; n1 < 16; ++n1) {
        ar[n1] = __builtin_nontemporal_load(&src[n1*16 + j]);
        ai[n1] = 0.f;
    }
    fft256_4step<0, false>(ar, ai, Tr, Ti, g * 272, j);
    __half2* dst = W1 + row * 256;
#pragma unroll
    for (int k2 = 0; k2 < 16; ++k2) dst[k2*16 + j] = __floats2half2_rn(ar[k2], ai[k2]);
}

// ---------------------------------------------------------------------------
// P2+P3 fused: per 16-col tile, forward col FFT ONCE (kept in registers),
// then for GROUP slices: mul by F_s/65536, inverse col FFT, write Z_s.
// ---------------------------------------------------------------------------
template<int GROUP>
__global__ __launch_bounds__(256) void k_col_fused(const __half2* __restrict__ W1,
                                                   const float* __restrict__ fre,
                                                   const float* __restrict__ fim,
                                                   __half2* __restrict__ Z, int s0) {
    __shared__ float Tr[4384], Ti[4384];
    int t = threadIdx.x, c = t & 15, j = t >> 4;
    int m0 = blockIdx.x * 16, img = blockIdx.y;
    const __half2* src = W1 + (size_t)img * 65536 + m0 + c;
    const float scale = 1.f / 65536.f;      // full ifft2 normalization
    float ar[16], ai[16];
#pragma unroll
    for (int n1 = 0; n1 < 16; ++n1) {
        __half2 v = src[(n1*16 + j) * 256];
        ar[n1] = __low2float(v); ai[n1] = __high2float(v);
    }
    fft256_4step<0, true>(ar, ai, Tr, Ti, c * 274, j);
    float xr[16], xi[16];
#pragma unroll
    for (int k2 = 0; k2 < 16; ++k2) { xr[k2] = ar[k2]; xi[k2] = ai[k2]; }

    for (int sl = 0; sl < GROUP; ++sl) {
        int s = s0 + sl;
        const float* fr = fre + (size_t)s * 65536 + m0 + c;
        const float* fi = fim + (size_t)s * 65536 + m0 + c;
#pragma unroll
        for (int k2 = 0; k2 < 16; ++k2) {
            int off = (16*k2 + j) * 256;
            float wr = fr[off] * scale, wi = fi[off] * scale;
            ar[k2] = xr[k2]*wr - xi[k2]*wi;
            ai[k2] = xr[k2]*wi + xi[k2]*wr;
        }
        fft256_4step<1, true>(ar, ai, Tr, Ti, c * 274, j);
        __half2* dst = Z + (size_t)sl * 8388608 + (size_t)img * 65536 + m0 + c;
#pragma unroll
        for (int k2 = 0; k2 < 16; ++k2)
            dst[(16*k2 + j) * 256] = __floats2half2_rn(ar[k2], ai[k2]);
    }
}

// ---------------------------------------------------------------------------
// P4 (batched over GROUP slices): inverse row FFT of Z_sl, |.| -> out.
// out is write-once-never-read: nontemporal stores keep the 256 MB out
// stream from evicting the Z slice-group (134 MB) from L3.
// ---------------------------------------------------------------------------
__global__ __launch_bounds__(256) void k_row_ifft_abs(const __half2* __restrict__ Z,
                                                      float* __restrict__ out, int s0) {
    __shared__ float Tr[4352], Ti[4352];
    int t = threadIdx.x, g = t >> 4, j = t & 15;
    int sl = blockIdx.y;
    long row = (long)blockIdx.x * 16 + g;   // img*256 + n
    long img = row >> 8, n = row & 255;
    const __half2* src = Z + (size_t)sl * 8388608 + row * 256;
    float ar[16], ai[16];
#pragma unroll
    for (int n1 = 0; n1 < 16; ++n1) {
        __half2 v = src[n1*16 + j];
        ar[n1] = __low2float(v); ai[n1] = __high2float(v);
    }
    fft256_4step<1, false>(ar, ai, Tr, Ti, g * 272, j);
    float* dst = out + ((img * 8 + (long)(s0 + sl)) * 256 + n) * 256;
#pragma unroll
    for (int k2 = 0; k2 < 16; ++k2)
        __builtin_nontemporal_store(sqrtf(ar[k2]*ar[k2] + ai[k2]*ai[k2]),
                                    &dst[k2*16 + j]);
}

// ---------------------------------------------------------------------------
extern "C" void kernel_launch(void* const* d_in, const int* in_sizes, int n_in,
                              void* d_out, int out_size, void* d_ws, size_t ws_size,
                              hipStream_t stream) {
    const float* x   = (const float*)d_in[0];   // [8,16,256,256] f32
    const float* fre = (const float*)d_in[1];   // [8,256,256]
    const float* fim = (const float*)d_in[2];   // [8,256,256]
    float* out = (float*)d_out;                 // [8,16,8,256,256] f32

    const size_t IMG_ELEMS = (size_t)128 * 65536;
    __half2* W1 = (__half2*)d_ws;                          // 33.5 MB
    __half2* Z  = (__half2*)((char*)d_ws + IMG_ELEMS * 4); // 33.5 MB x GROUP

    k_row_fft<<<dim3(2048), 256, 0, stream>>>(x, W1);

    if (ws_size >= IMG_ELEMS * 4 * 5) {        // W1 + 4 Z slices = 168 MB
        for (int s0 = 0; s0 < 8; s0 += 4) {
            k_col_fused<4><<<dim3(16, 128), 256, 0, stream>>>(W1, fre, fim, Z, s0);
            k_row_ifft_abs<<<dim3(2048, 4), 256, 0, stream>>>(Z, out, s0);
        }
    } else {                                   // fallback: slice-at-a-time
        for (int s = 0; s < 8; ++s) {
            k_col_fused<1><<<dim3(16, 128), 256, 0, stream>>>(W1, fre, fim, Z, s);
            k_row_ifft_abs<<<dim3(2048, 1), 256, 0, stream>>>(Z, out, s);
        }
    }
}